// Round 2
// baseline (216.230 us; speedup 1.0000x reference)
//
#include <hip/hip_runtime.h>

typedef float v4f __attribute__((ext_vector_type(4)));

#define NB 32
#define NT 512
#define ND 384
#define MAX_OUT 3584            // T * (DUR_MAX-1)
#define NV (ND / 4)             // 96 float4 per row
#define TPR (NV / 2)            // 48 threads per row (2 float4 = 32 B each)
#define BLK 256

// Kernel 1: per-batch inclusive scan of durations + scatter inverse index map.
__global__ __launch_bounds__(NT) void lr_scan_scatter(
    const int* __restrict__ dur, int* __restrict__ totals, int* __restrict__ idxmap)
{
    __shared__ int s[NT];
    const int b = blockIdx.x;
    const int t = threadIdx.x;

    int d = dur[b * NT + t];
    d = d > 0 ? d : 0;            // patched = max(round(1.0*d),0) == max(d,0)
    s[t] = d;
    __syncthreads();

    #pragma unroll
    for (int off = 1; off < NT; off <<= 1) {
        int v = (t >= off) ? s[t - off] : 0;
        __syncthreads();
        s[t] += v;
        __syncthreads();
    }
    const int cum = s[t];
    const int start = cum - d;

    int* base = idxmap + b * MAX_OUT;
    for (int j = 0; j < d; ++j) base[start + j] = t;

    if (t == NT - 1) totals[b] = cum;
}

// Kernel 2: one thread per 32 B of output (2 float4). Gather or zero-fill.
__global__ __launch_bounds__(BLK) void lr_gather2(
    const v4f* __restrict__ in, const int* __restrict__ totals,
    const int* __restrict__ idxmap, v4f* __restrict__ out)
{
    // XCD swizzle: round-robin dispatch sends blk%8 to XCD (blk%8); remap so
    // each XCD owns a contiguous 1/8 of the output -> its input slice
    // (4 batches ~= 3 MB) stays resident in its 4 MB L2.
    const unsigned g8 = gridDim.x >> 3;
    const unsigned nb = (blockIdx.x & 7u) * g8 + (blockIdx.x >> 3);
    const unsigned g  = nb * BLK + threadIdx.x;

    const unsigned row = g / TPR;            // (b,pos) flattened
    const unsigned col = g - row * TPR;      // [0,48)
    const unsigned b   = row / MAX_OUT;
    const unsigned pos = row - b * MAX_OUT;

    // Independent loads issued concurrently (idxmap read is always in-bounds;
    // its value is only used when pos < tot).
    const int tot = totals[b];
    const int idx = idxmap[row];

    v4f r0 = {0.f, 0.f, 0.f, 0.f};
    v4f r1 = {0.f, 0.f, 0.f, 0.f};
    if ((int)pos < tot) {
        const v4f* src = in + (unsigned)(b * NT + idx) * NV + col * 2u;
        r0 = src[0];
        r1 = src[1];
    }
    // Non-temporal: the 176 MB output stream must not thrash L2.
    v4f* dst = out + (size_t)g * 2u;
    __builtin_nontemporal_store(r0, dst);
    __builtin_nontemporal_store(r1, dst + 1);
}

extern "C" void kernel_launch(void* const* d_in, const int* in_sizes, int n_in,
                              void* d_out, int out_size, void* d_ws, size_t ws_size,
                              hipStream_t stream)
{
    const float* x   = (const float*)d_in[0];
    const int*   dur = (const int*)d_in[1];

    int* totals = (int*)d_ws;                    // NB ints
    int* idxmap = (int*)((char*)d_ws + 128);     // NB*MAX_OUT ints

    lr_scan_scatter<<<NB, NT, 0, stream>>>(dur, totals, idxmap);

    const unsigned n_thr = (unsigned)NB * MAX_OUT * TPR;   // 5,505,024
    lr_gather2<<<n_thr / BLK, BLK, 0, stream>>>(
        (const v4f*)x, totals, idxmap, (v4f*)d_out);
}

// Round 3
// 207.726 us; speedup vs baseline: 1.0409x; 1.0409x over previous
//
#include <hip/hip_runtime.h>

typedef float v4f __attribute__((ext_vector_type(4)));

#define NB 32
#define NT 512
#define ND 384
#define MAX_OUT 3584              // T * (DUR_MAX-1)
#define NV 96                     // float4 per row
#define TILE 64                   // output rows per gather block
#define BLK 256
#define PER (TILE * NV / BLK)     // 24 float4 per thread
#define TILES_PER_B (MAX_OUT / TILE)   // 56

// Kernel 1: per-batch inclusive scan (wave shuffles) + scatter inverse map.
__global__ __launch_bounds__(NT) void lr_scan_scatter(
    const int* __restrict__ dur, int* __restrict__ totals, int* __restrict__ idxmap)
{
    __shared__ int wsum[NT / 64];
    const int b = blockIdx.x;
    const int t = threadIdx.x;
    const int lane = t & 63;
    const int w = t >> 6;

    int d = dur[b * NT + t];
    d = d > 0 ? d : 0;            // patched = max(round(1.0*d),0) == max(d,0)

    // intra-wave inclusive scan
    int c = d;
    #pragma unroll
    for (int off = 1; off < 64; off <<= 1) {
        int v = __shfl_up(c, off, 64);
        if (lane >= off) c += v;
    }
    if (lane == 63) wsum[w] = c;
    __syncthreads();

    int add = 0;
    for (int i = 0; i < w; ++i) add += wsum[i];   // <=7 LDS reads
    const int cum = c + add;
    const int start = cum - d;

    int* base = idxmap + b * MAX_OUT;
    for (int j = 0; j < d; ++j) base[start + j] = t;

    if (t == NT - 1) totals[b] = cum;
}

// Kernel 2: block-per-64-row output tile; LDS-staged indices; 384 B/thread.
__global__ __launch_bounds__(BLK) void lr_gather(
    const v4f* __restrict__ in, const int* __restrict__ totals,
    const int* __restrict__ idxmap, v4f* __restrict__ out)
{
    // XCD swizzle: contiguous eighth of the output per XCD (grid % 8 == 0).
    const unsigned g8 = gridDim.x >> 3;
    const unsigned blk = (blockIdx.x & 7u) * g8 + (blockIdx.x >> 3);

    const unsigned b    = blk / TILES_PER_B;
    const unsigned tile = blk - b * TILES_PER_B;
    const unsigned row0 = tile * TILE;          // first output pos of tile

    __shared__ int sidx[TILE];
    __shared__ int stot;
    const int t = threadIdx.x;
    if (t < TILE) sidx[t] = idxmap[b * MAX_OUT + row0 + t];
    if (t == 0)   stot = totals[b];
    __syncthreads();

    const int nvalid = stot - (int)row0;        // valid rows in this tile
    const v4f* inb  = in  + (size_t)b * NT * NV;
    v4f*       outb = out + ((size_t)b * MAX_OUT + row0) * NV;

    if (nvalid >= TILE) {                       // fully valid tile
        #pragma unroll
        for (int k = 0; k < PER; ++k) {
            const int i = t + k * BLK;
            const int r = i / NV;
            const int c = i - r * NV;
            const v4f v = inb[sidx[r] * NV + c];
            __builtin_nontemporal_store(v, outb + i);
        }
    } else if (nvalid <= 0) {                   // fully zero tile: pure stream
        const v4f z = {0.f, 0.f, 0.f, 0.f};
        #pragma unroll
        for (int k = 0; k < PER; ++k)
            __builtin_nontemporal_store(z, outb + t + k * BLK);
    } else {                                    // boundary tile (one per batch)
        #pragma unroll
        for (int k = 0; k < PER; ++k) {
            const int i = t + k * BLK;
            const int r = i / NV;
            const int c = i - r * NV;
            v4f v = {0.f, 0.f, 0.f, 0.f};
            if (r < nvalid) v = inb[sidx[r] * NV + c];
            __builtin_nontemporal_store(v, outb + i);
        }
    }
}

extern "C" void kernel_launch(void* const* d_in, const int* in_sizes, int n_in,
                              void* d_out, int out_size, void* d_ws, size_t ws_size,
                              hipStream_t stream)
{
    const float* x   = (const float*)d_in[0];
    const int*   dur = (const int*)d_in[1];

    int* totals = (int*)d_ws;                   // NB ints
    int* idxmap = (int*)((char*)d_ws + 128);    // NB*MAX_OUT ints

    lr_scan_scatter<<<NB, NT, 0, stream>>>(dur, totals, idxmap);

    const unsigned n_blk = (unsigned)NB * TILES_PER_B;   // 1792
    lr_gather<<<n_blk, BLK, 0, stream>>>(
        (const v4f*)x, totals, idxmap, (v4f*)d_out);
}

// Round 5
// 206.593 us; speedup vs baseline: 1.0467x; 1.0055x over previous
//
#include <hip/hip_runtime.h>

typedef float v4f __attribute__((ext_vector_type(4)));

#define NB 32
#define NT 512
#define ND 384
#define MAX_OUT 3584              // T * (DUR_MAX-1)
#define NV 96                     // float4 per row
#define TILE 64                   // output rows per block
#define BLK 256
#define PER (TILE * NV / BLK)     // 24 float4 per thread
#define TILES_PER_B (MAX_OUT / TILE)   // 56

// Single fused kernel: each block owns a 64-row output tile of one batch.
// Recomputes the batch's duration cumsum in LDS, binary-searches its 64
// source indices (10 steps: answer space is [0,512] = 513 values!), then
// streams 384 B/thread (copy or zero).
__global__ __launch_bounds__(BLK) void lr_fused(
    const int* __restrict__ dur, const v4f* __restrict__ in, v4f* __restrict__ out)
{
    // XCD swizzle: contiguous eighth of the output per XCD (grid % 8 == 0).
    const unsigned g8  = gridDim.x >> 3;
    const unsigned blk = (blockIdx.x & 7u) * g8 + (blockIdx.x >> 3);
    const unsigned b    = blk / TILES_PER_B;
    const unsigned tile = blk - b * TILES_PER_B;
    const unsigned row0 = tile * TILE;

    __shared__ int cum[NT];       // inclusive cumsum of clamped durations
    __shared__ int wpart[BLK / 64];
    __shared__ int sidx[TILE];

    const int t    = threadIdx.x;
    const int lane = t & 63;
    const int w    = t >> 6;

    // ---- scan: 2 durations per thread (elements 2t, 2t+1), wave shuffles ----
    const int2 dd = ((const int2*)(dur + b * NT))[t];
    const int d0 = dd.x > 0 ? dd.x : 0;   // patched = max(round(1.0*d),0)
    const int d1 = dd.y > 0 ? dd.y : 0;
    const int s = d0 + d1;
    int c = s;
    #pragma unroll
    for (int off = 1; off < 64; off <<= 1) {
        int v = __shfl_up(c, off, 64);
        if (lane >= off) c += v;
    }
    if (lane == 63) wpart[w] = c;
    __syncthreads();
    int add = 0;
    #pragma unroll
    for (int i = 0; i < BLK / 64; ++i) if (i < w) add += wpart[i];
    const int epfx = add + c - s;         // exclusive prefix of this pair
    cum[2 * t]     = epfx + d0;
    cum[2 * t + 1] = epfx + d0 + d1;
    __syncthreads();

    const int total = cum[NT - 1];

    // ---- searchsorted(side='right'): answer in [0,512] -> 10 steps ----
    if (t < TILE) {
        const int pos = (int)row0 + t;
        int lo = 0, hi = NT;
        #pragma unroll
        for (int step = 0; step < 10; ++step) {
            if (lo < hi) {
                const int mid = (lo + hi) >> 1;    // mid <= 511, in-bounds
                if (cum[mid] <= pos) lo = mid + 1; else hi = mid;
            }
        }
        sidx[t] = lo < NT - 1 ? lo : NT - 1;       // clip (masked anyway)
    }
    __syncthreads();

    // ---- stream the tile ----
    const int nvalid = total - (int)row0;
    const v4f* inb  = in  + (size_t)b * NT * NV;
    v4f*       outb = out + ((size_t)b * MAX_OUT + row0) * NV;

    if (nvalid >= TILE) {                        // fully valid tile
        #pragma unroll
        for (int k = 0; k < PER; ++k) {
            const int i = t + k * BLK;
            const int r = i / NV;
            const int c2 = i - r * NV;
            const v4f v = inb[sidx[r] * NV + c2];
            __builtin_nontemporal_store(v, outb + i);
        }
    } else if (nvalid <= 0) {                    // fully zero tile
        const v4f z = {0.f, 0.f, 0.f, 0.f};
        #pragma unroll
        for (int k = 0; k < PER; ++k)
            __builtin_nontemporal_store(z, outb + t + k * BLK);
    } else {                                     // boundary tile (one per batch)
        #pragma unroll
        for (int k = 0; k < PER; ++k) {
            const int i = t + k * BLK;
            const int r = i / NV;
            const int c2 = i - r * NV;
            v4f v = {0.f, 0.f, 0.f, 0.f};
            if (r < nvalid) v = inb[sidx[r] * NV + c2];
            __builtin_nontemporal_store(v, outb + i);
        }
    }
}

extern "C" void kernel_launch(void* const* d_in, const int* in_sizes, int n_in,
                              void* d_out, int out_size, void* d_ws, size_t ws_size,
                              hipStream_t stream)
{
    const int* dur = (const int*)d_in[1];
    const v4f* x   = (const v4f*)d_in[0];

    const unsigned n_blk = (unsigned)NB * TILES_PER_B;   // 1792
    lr_fused<<<n_blk, BLK, 0, stream>>>(dur, x, (v4f*)d_out);
}